// Round 1
// baseline (1118.711 us; speedup 1.0000x reference)
//
#include <hip/hip_runtime.h>

typedef __bf16 bf16;
typedef __bf16 bf16x4 __attribute__((ext_vector_type(4)));
typedef __bf16 bf16x8 __attribute__((ext_vector_type(8)));
typedef float f32x4 __attribute__((ext_vector_type(4)));

#define HID 4096
#define QKV_N 6144
#define NTOK 4096   // b*s = 4*1024

// async global->LDS, 16B per lane. LDS side is wave-uniform base + lane*16;
// our layouts are arranged so lane l's LDS target == base + l*16 exactly.
__device__ __forceinline__ void gload_lds16(const bf16* g, bf16* l) {
  __builtin_amdgcn_global_load_lds(
      (__attribute__((address_space(1))) void*)(g),
      (__attribute__((address_space(3))) void*)(l), 16, 0, 0);
}

// ---------------- fp32 -> bf16 convert ----------------
__global__ void cvt_kernel(const float4* __restrict__ s, bf16x4* __restrict__ d) {
  int i = blockIdx.x * blockDim.x + threadIdx.x;
  float4 v = s[i];
  bf16x4 o;
  o[0] = (bf16)v.x; o[1] = (bf16)v.y; o[2] = (bf16)v.z; o[3] = (bf16)v.w;
  d[i] = o;
}

// ---------------- GEMM: C = A @ B^T (A: MxK, B: NxK, both bf16 K-major) ----------------
// m97 structure: 128x128 tile, BK=64, 4 waves each 64x64 (4x4 of 16x16x32 MFMA).
template <typename OutT>
__global__ __launch_bounds__(256) void gemm_bt(
    const bf16* __restrict__ A, const bf16* __restrict__ Bm,
    OutT* __restrict__ C, int M, int N, int K)
{
  __shared__ bf16 As[128 * 64];
  __shared__ bf16 Bs[128 * 64];
  const int tid = threadIdx.x;
  const int w = tid >> 6, l = tid & 63;
  const int quad = l >> 4, lane16 = l & 15;
  const int row0 = blockIdx.y * 128, col0 = blockIdx.x * 128;
  const int wm = (w & 1) * 64, wn = (w >> 1) * 64;
  const int lrow = l >> 3, lk = (l & 7) * 8;

  f32x4 acc[4][4];
#pragma unroll
  for (int a = 0; a < 4; ++a)
#pragma unroll
    for (int b = 0; b < 4; ++b) acc[a][b] = (f32x4){0.f, 0.f, 0.f, 0.f};

  for (int k0 = 0; k0 < K; k0 += 64) {
#pragma unroll
    for (int r = 0; r < 4; ++r) {
      int i = r * 4 + w;  // wave-issue id 0..15; covers 8 rows of 64 k each
      gload_lds16(A + (size_t)(row0 + i * 8 + lrow) * K + k0 + lk, &As[i * 512 + l * 8]);
      gload_lds16(Bm + (size_t)(col0 + i * 8 + lrow) * K + k0 + lk, &Bs[i * 512 + l * 8]);
    }
    __syncthreads();
#pragma unroll
    for (int kk = 0; kk < 2; ++kk) {
      bf16x8 af[4], bfr[4];
#pragma unroll
      for (int im = 0; im < 4; ++im)
        af[im] = *(const bf16x8*)&As[(wm + im * 16 + lane16) * 64 + kk * 32 + quad * 8];
#pragma unroll
      for (int in_ = 0; in_ < 4; ++in_)
        bfr[in_] = *(const bf16x8*)&Bs[(wn + in_ * 16 + lane16) * 64 + kk * 32 + quad * 8];
#pragma unroll
      for (int im = 0; im < 4; ++im)
#pragma unroll
        for (int in_ = 0; in_ < 4; ++in_)
          acc[im][in_] = __builtin_amdgcn_mfma_f32_16x16x32_bf16(af[im], bfr[in_], acc[im][in_], 0, 0, 0);
    }
    __syncthreads();
  }
  // epilogue: D[row=quad*4+reg][col=lane16] (m89-verified mapping)
#pragma unroll
  for (int im = 0; im < 4; ++im) {
#pragma unroll
    for (int r = 0; r < 4; ++r) {
      int row = row0 + wm + im * 16 + quad * 4 + r;
      OutT* cp = C + (size_t)row * N + col0 + wn;
#pragma unroll
      for (int in_ = 0; in_ < 4; ++in_)
        cp[in_ * 16 + lane16] = (OutT)acc[im][in_][r];
    }
  }
}

// ---------------- per-head RMSNorm + RoPE, in-place on qkv (bf16) ----------------
// grid: NTOK * 40 blocks of 64 threads. slot 0..31 = q heads, 32..39 = k heads.
__global__ void norm_rope_kernel(bf16* __restrict__ qkv, const int* __restrict__ pos,
                                 const float* __restrict__ qw, const float* __restrict__ kw)
{
  int blk = blockIdx.x;
  int tok = blk / 40;
  int slot = blk % 40;
  int d = threadIdx.x;  // 0..63 (pair index)
  bf16* base;
  const float* w;
  if (slot < 32) { base = qkv + (size_t)tok * QKV_N + slot * 128; w = qw; }
  else           { base = qkv + (size_t)tok * QKV_N + HID + (slot - 32) * 128; w = kw; }
  float x1 = (float)base[d], x2 = (float)base[d + 64];
  float ss = x1 * x1 + x2 * x2;
#pragma unroll
  for (int m = 1; m < 64; m <<= 1) ss += __shfl_xor(ss, m, 64);
  float rn = rsqrtf(ss * (1.0f / 128.0f) + 1e-6f);
  x1 = x1 * rn * w[d];
  x2 = x2 * rn * w[d + 64];
  int p = pos[tok & 1023];
  float invf = powf(10000.0f, -(float)d * (1.0f / 64.0f));
  float ang = (float)p * invf;
  float c = cosf(ang), sn = sinf(ang);
  base[d]      = (bf16)(x1 * c - x2 * sn);
  base[d + 64] = (bf16)(x2 * c + x1 * sn);
}

// ---------------- flash attention (causal, GQA) ----------------
// grid: (16 q-tiles of 64 rows, 128 b*h). block = 256 (4 waves, 16 q-rows each).
__global__ __launch_bounds__(256) void flash_kernel(
    const bf16* __restrict__ qkv, bf16* __restrict__ attn)
{
  __shared__ bf16 Qs[64 * 128];
  __shared__ bf16 Ks[64 * 128];
  __shared__ bf16 Vt[128 * 72];   // [d][t], stride 72 to break bank alignment
  __shared__ bf16 Ps[4][16 * 64]; // per-wave P (C-layout -> A-layout round trip)

  const int qt = blockIdx.x;      // 0..15
  const int bh = blockIdx.y;      // 0..127
  const int batch = bh >> 5;
  const int qh = bh & 31;
  const int kvh = qh >> 2;
  const int tid = threadIdx.x;
  const int w = tid >> 6, l = tid & 63;
  const int quad = l >> 4, lane16 = l & 15;
  const size_t tok0 = (size_t)batch * 1024;
  const int q0 = qt * 64;

  // stage Q tile (64 x 128)
#pragma unroll
  for (int r = 0; r < 4; ++r) {
    int i = r * 4 + w;  // 0..15, 4 rows each
    const bf16* g = qkv + (tok0 + q0 + i * 4 + (l >> 4)) * QKV_N + qh * 128 + (l & 15) * 8;
    gload_lds16(g, &Qs[i * 512 + l * 8]);
  }

  f32x4 O[8];
#pragma unroll
  for (int id = 0; id < 8; ++id) O[id] = (f32x4){0.f, 0.f, 0.f, 0.f};
  float m_run[4], l_run[4];
#pragma unroll
  for (int r = 0; r < 4; ++r) { m_run[r] = -1e30f; l_run[r] = 0.f; }

  const float scale = 0.08838834764831845f;  // 1/sqrt(128)

  for (int j = 0; j <= qt; ++j) {
    // stage K tile (64 x 128)
#pragma unroll
    for (int r = 0; r < 4; ++r) {
      int i = r * 4 + w;
      const bf16* g = qkv + (tok0 + j * 64 + i * 4 + (l >> 4)) * QKV_N + HID + kvh * 128 + (l & 15) * 8;
      gload_lds16(g, &Ks[i * 512 + l * 8]);
    }
    // stage V transposed: wave covers 64 t-values x one d-octet per iteration
#pragma unroll
    for (int c = 0; c < 4; ++c) {
      int dg = c * 4 + w;  // 0..15
      int d0 = dg * 8;
      const bf16* g = qkv + (tok0 + j * 64 + l) * QKV_N + HID + 1024 + kvh * 128 + d0;
      bf16x8 v = *(const bf16x8*)g;
#pragma unroll
      for (int e = 0; e < 8; ++e) Vt[(d0 + e) * 72 + l] = v[e];
    }
    __syncthreads();

    // S = Q K^T for this wave's 16 q-rows
    f32x4 s[4];
#pragma unroll
    for (int in_ = 0; in_ < 4; ++in_) s[in_] = (f32x4){0.f, 0.f, 0.f, 0.f};
#pragma unroll
    for (int kk = 0; kk < 4; ++kk) {
      bf16x8 a = *(const bf16x8*)&Qs[(w * 16 + lane16) * 128 + kk * 32 + quad * 8];
#pragma unroll
      for (int in_ = 0; in_ < 4; ++in_) {
        bf16x8 b = *(const bf16x8*)&Ks[(in_ * 16 + lane16) * 128 + kk * 32 + quad * 8];
        s[in_] = __builtin_amdgcn_mfma_f32_16x16x32_bf16(a, b, s[in_], 0, 0, 0);
      }
    }

    // causal mask + scale + online softmax
#pragma unroll
    for (int r = 0; r < 4; ++r) {
      int q_abs = q0 + w * 16 + quad * 4 + r;
      float rm = -1e30f;
#pragma unroll
      for (int in_ = 0; in_ < 4; ++in_) {
        int t_abs = j * 64 + in_ * 16 + lane16;
        float v = s[in_][r] * scale;
        v = (t_abs <= q_abs) ? v : -1e30f;
        s[in_][r] = v;
        rm = fmaxf(rm, v);
      }
#pragma unroll
      for (int m = 1; m < 16; m <<= 1) rm = fmaxf(rm, __shfl_xor(rm, m, 64));
      float mn = fmaxf(m_run[r], rm);
      float alpha = __expf(m_run[r] - mn);
      m_run[r] = mn;
      float rs = 0.f;
#pragma unroll
      for (int in_ = 0; in_ < 4; ++in_) {
        float pv = __expf(s[in_][r] - mn);
        s[in_][r] = pv;
        rs += pv;
      }
#pragma unroll
      for (int m = 1; m < 16; m <<= 1) rs += __shfl_xor(rs, m, 64);
      l_run[r] = l_run[r] * alpha + rs;
#pragma unroll
      for (int id = 0; id < 8; ++id) O[id][r] *= alpha;
#pragma unroll
      for (int in_ = 0; in_ < 4; ++in_)
        Ps[w][(quad * 4 + r) * 64 + in_ * 16 + lane16] = (bf16)s[in_][r];
    }

    // O += P @ V
#pragma unroll
    for (int kt = 0; kt < 2; ++kt) {
      bf16x8 a = *(const bf16x8*)&Ps[w][lane16 * 64 + kt * 32 + quad * 8];
#pragma unroll
      for (int id = 0; id < 8; ++id) {
        bf16x8 b = *(const bf16x8*)&Vt[(id * 16 + lane16) * 72 + kt * 32 + quad * 8];
        O[id] = __builtin_amdgcn_mfma_f32_16x16x32_bf16(a, b, O[id], 0, 0, 0);
      }
    }
    __syncthreads();
  }

  // epilogue: O /= l, write bf16
#pragma unroll
  for (int r = 0; r < 4; ++r) {
    float inv = 1.0f / l_run[r];
    int row = q0 + w * 16 + quad * 4 + r;
    bf16* orow = attn + (tok0 + row) * (size_t)HID + qh * 128;
#pragma unroll
    for (int id = 0; id < 8; ++id) orow[id * 16 + lane16] = (bf16)(O[id][r] * inv);
  }
}

// ---------------- launch ----------------
extern "C" void kernel_launch(void* const* d_in, const int* in_sizes, int n_in,
                              void* d_out, int out_size, void* d_ws, size_t ws_size,
                              hipStream_t stream) {
  const float* h    = (const float*)d_in[0];
  const int*   pos  = (const int*)d_in[1];
  const float* wqkv = (const float*)d_in[2];
  const float* wo   = (const float*)d_in[3];
  const float* qw   = (const float*)d_in[4];
  const float* kw   = (const float*)d_in[5];
  float* out = (float*)d_out;

  bf16* hb    = (bf16*)d_ws;            // 16,777,216
  bf16* wqkvb = hb + 16777216;          // 25,165,824
  bf16* wob   = wqkvb + 25165824;       // 16,777,216
  bf16* qkvb  = wob + 16777216;         // 25,165,824
  bf16* attnb = qkvb + 25165824;        // 16,777,216  (total 192 MiB)

  cvt_kernel<<<16384, 256, 0, stream>>>((const float4*)h, (bf16x4*)hb);
  cvt_kernel<<<24576, 256, 0, stream>>>((const float4*)wqkv, (bf16x4*)wqkvb);
  cvt_kernel<<<16384, 256, 0, stream>>>((const float4*)wo, (bf16x4*)wob);

  gemm_bt<bf16><<<dim3(48, 32), 256, 0, stream>>>(hb, wqkvb, qkvb, NTOK, QKV_N, HID);

  norm_rope_kernel<<<NTOK * 40, 64, 0, stream>>>(qkvb, pos, qw, kw);

  flash_kernel<<<dim3(16, 128), 256, 0, stream>>>(qkvb, attnb);

  gemm_bt<float><<<dim3(32, 32), 256, 0, stream>>>(attnb, wob, out, NTOK, HID, HID);
}

// Round 2
// 874.951 us; speedup vs baseline: 1.2786x; 1.2786x over previous
//
#include <hip/hip_runtime.h>

typedef __bf16 bf16;
typedef __bf16 bf16x4 __attribute__((ext_vector_type(4)));
typedef __bf16 bf16x8 __attribute__((ext_vector_type(8)));
typedef float f32x4 __attribute__((ext_vector_type(4)));

#define HID 4096
#define QKV_N 6144
#define NTOK 4096   // b*s = 4*1024

// async global->LDS, 16B per lane. LDS side is wave-uniform base + lane*16.
__device__ __forceinline__ void gload_lds16(const bf16* g, bf16* l) {
  __builtin_amdgcn_global_load_lds(
      (__attribute__((address_space(1))) void*)(g),
      (__attribute__((address_space(3))) void*)(l), 16, 0, 0);
}

// ---------------- fp32 -> bf16 convert ----------------
__global__ void cvt_kernel(const float4* __restrict__ s, bf16x4* __restrict__ d) {
  int i = blockIdx.x * blockDim.x + threadIdx.x;
  float4 v = s[i];
  bf16x4 o;
  o[0] = (bf16)v.x; o[1] = (bf16)v.y; o[2] = (bf16)v.z; o[3] = (bf16)v.w;
  d[i] = o;
}

// ---------------- GEMM: C = A @ B^T (A: MxK, B: NxK, both bf16 K-major) ----------------
// 128x128 tile, BK=64, 4 waves each 64x64 (4x4 of 16x16x32 MFMA).
// LDS layout XOR-swizzled: row r's physical octet slot s holds global octet s^(r&7),
// arranged at staging time by permuting each lane's global fetch address. This
// spreads the 16 lane16-rows of each ds_read_b128 across all 8 bank-quads.
template <typename OutT>
__global__ __launch_bounds__(256) void gemm_bt(
    const bf16* __restrict__ A, const bf16* __restrict__ Bm,
    OutT* __restrict__ C, int M, int N, int K)
{
  __shared__ bf16 As[128 * 64];
  __shared__ bf16 Bs[128 * 64];
  const int tid = threadIdx.x;
  const int w = tid >> 6, l = tid & 63;
  const int quad = l >> 4, lane16 = l & 15;
  const int row0 = blockIdx.y * 128, col0 = blockIdx.x * 128;
  const int wm = (w & 1) * 64, wn = (w >> 1) * 64;
  const int lrow = l >> 3;                       // row within 8-row chunk
  const int lkswz = ((l & 7) ^ lrow) * 8;        // swizzled k-octet offset (elements)
  const int sw = lane16 & 7;                     // read-side swizzle key

  f32x4 acc[4][4];
#pragma unroll
  for (int a = 0; a < 4; ++a)
#pragma unroll
    for (int b = 0; b < 4; ++b) acc[a][b] = (f32x4){0.f, 0.f, 0.f, 0.f};

  for (int k0 = 0; k0 < K; k0 += 64) {
#pragma unroll
    for (int r = 0; r < 4; ++r) {
      int i = r * 4 + w;  // chunk id 0..15; chunk covers rows i*8..i*8+7
      gload_lds16(A + (size_t)(row0 + i * 8 + lrow) * K + k0 + lkswz, &As[i * 512 + l * 8]);
      gload_lds16(Bm + (size_t)(col0 + i * 8 + lrow) * K + k0 + lkswz, &Bs[i * 512 + l * 8]);
    }
    __syncthreads();
#pragma unroll
    for (int kk = 0; kk < 2; ++kk) {
      bf16x8 af[4], bfr[4];
#pragma unroll
      for (int im = 0; im < 4; ++im)
        af[im] = *(const bf16x8*)&As[(wm + im * 16 + lane16) * 64 + (((kk * 4 + quad) ^ sw) * 8)];
#pragma unroll
      for (int in_ = 0; in_ < 4; ++in_)
        bfr[in_] = *(const bf16x8*)&Bs[(wn + in_ * 16 + lane16) * 64 + (((kk * 4 + quad) ^ sw) * 8)];
#pragma unroll
      for (int im = 0; im < 4; ++im)
#pragma unroll
        for (int in_ = 0; in_ < 4; ++in_)
          acc[im][in_] = __builtin_amdgcn_mfma_f32_16x16x32_bf16(af[im], bfr[in_], acc[im][in_], 0, 0, 0);
    }
    __syncthreads();
  }
  // epilogue: D[row=quad*4+reg][col=lane16] (m89-verified mapping)
#pragma unroll
  for (int im = 0; im < 4; ++im) {
#pragma unroll
    for (int r = 0; r < 4; ++r) {
      int row = row0 + wm + im * 16 + quad * 4 + r;
      OutT* cp = C + (size_t)row * N + col0 + wn;
#pragma unroll
      for (int in_ = 0; in_ < 4; ++in_)
        cp[in_ * 16 + lane16] = (OutT)acc[im][in_][r];
    }
  }
}

// ---------------- per-head RMSNorm + RoPE, in-place on qkv (bf16) ----------------
// 256-thread blocks, 4 (tok,slot) units per block (one per wave).
__global__ __launch_bounds__(256) void norm_rope_kernel(
    bf16* __restrict__ qkv, const int* __restrict__ pos,
    const float* __restrict__ qw, const float* __restrict__ kw)
{
  int g = blockIdx.x * 4 + (threadIdx.x >> 6);
  int tok = g / 40;
  int slot = g % 40;
  int d = threadIdx.x & 63;  // pair index
  bf16* base;
  const float* w;
  if (slot < 32) { base = qkv + (size_t)tok * QKV_N + slot * 128; w = qw; }
  else           { base = qkv + (size_t)tok * QKV_N + HID + (slot - 32) * 128; w = kw; }
  float x1 = (float)base[d], x2 = (float)base[d + 64];
  float ss = x1 * x1 + x2 * x2;
#pragma unroll
  for (int m = 1; m < 64; m <<= 1) ss += __shfl_xor(ss, m, 64);
  float rn = rsqrtf(ss * (1.0f / 128.0f) + 1e-6f);
  x1 = x1 * rn * w[d];
  x2 = x2 * rn * w[d + 64];
  int p = pos[tok & 1023];
  float invf = exp2f(-0.20762050593045952f * (float)d);
  float ang = (float)p * invf;
  float sn, c;
  sincosf(ang, &sn, &c);
  base[d]      = (bf16)(x1 * c - x2 * sn);
  base[d + 64] = (bf16)(x2 * c + x1 * sn);
}

// ---------------- flash attention (causal, GQA) ----------------
// grid: (16 q-tiles of 64 rows, 128 b*h). block = 256 (4 waves, 16 q-rows each).
__global__ __launch_bounds__(256) void flash_kernel(
    const bf16* __restrict__ qkv, bf16* __restrict__ attn)
{
  __shared__ bf16 Qs[64 * 128];   // XOR-swizzled rows (low-3 of 16 octet slots)
  __shared__ bf16 Ks[64 * 128];   // XOR-swizzled
  __shared__ bf16 Vt[128 * 72];   // [d][t], stride 72 (2-way banks = free)
  __shared__ bf16 Ps[4][16 * 72]; // per-wave P, stride 72 to break row alias

  const int qt = blockIdx.x;      // 0..15
  const int bh = blockIdx.y;      // 0..127
  const int batch = bh >> 5;
  const int qh = bh & 31;
  const int kvh = qh >> 2;
  const int tid = threadIdx.x;
  const int w = tid >> 6, l = tid & 63;
  const int quad = l >> 4, lane16 = l & 15;
  const int sw = lane16 & 7;
  const size_t tok0 = (size_t)batch * 1024;
  const int q0 = qt * 64;

  // stage Q tile (64 x 128), swizzled: chunk i covers rows i*4..i*4+3
#pragma unroll
  for (int r = 0; r < 4; ++r) {
    int i = r * 4 + w;  // 0..15
    int rloc = i * 4 + (l >> 4);                 // row in tile
    int o = (l & 15) ^ (rloc & 7);               // global octet for this slot
    const bf16* g = qkv + (tok0 + q0 + rloc) * QKV_N + qh * 128 + o * 8;
    gload_lds16(g, &Qs[i * 512 + l * 8]);
  }

  f32x4 O[8];
#pragma unroll
  for (int id = 0; id < 8; ++id) O[id] = (f32x4){0.f, 0.f, 0.f, 0.f};
  float m_run[4], l_run[4];
#pragma unroll
  for (int r = 0; r < 4; ++r) { m_run[r] = -1e30f; l_run[r] = 0.f; }

  const float scale = 0.08838834764831845f;  // 1/sqrt(128)

  for (int j = 0; j <= qt; ++j) {
    // stage K tile (64 x 128), swizzled
#pragma unroll
    for (int r = 0; r < 4; ++r) {
      int i = r * 4 + w;
      int rloc = i * 4 + (l >> 4);
      int o = (l & 15) ^ (rloc & 7);
      const bf16* g = qkv + (tok0 + j * 64 + rloc) * QKV_N + HID + kvh * 128 + o * 8;
      gload_lds16(g, &Ks[i * 512 + l * 8]);
    }
    // stage V transposed: [d][t] with stride 72
#pragma unroll
    for (int c = 0; c < 4; ++c) {
      int dg = c * 4 + w;  // 0..15
      int d0 = dg * 8;
      const bf16* g = qkv + (tok0 + j * 64 + l) * QKV_N + HID + 1024 + kvh * 128 + d0;
      bf16x8 v = *(const bf16x8*)g;
#pragma unroll
      for (int e = 0; e < 8; ++e) Vt[(d0 + e) * 72 + l] = v[e];
    }
    __syncthreads();

    // S = Q K^T for this wave's 16 q-rows
    f32x4 s[4];
#pragma unroll
    for (int in_ = 0; in_ < 4; ++in_) s[in_] = (f32x4){0.f, 0.f, 0.f, 0.f};
#pragma unroll
    for (int kk = 0; kk < 4; ++kk) {
      bf16x8 a = *(const bf16x8*)&Qs[(w * 16 + lane16) * 128 + (((kk * 4 + quad) ^ sw) * 8)];
#pragma unroll
      for (int in_ = 0; in_ < 4; ++in_) {
        bf16x8 b = *(const bf16x8*)&Ks[(in_ * 16 + lane16) * 128 + (((kk * 4 + quad) ^ sw) * 8)];
        s[in_] = __builtin_amdgcn_mfma_f32_16x16x32_bf16(a, b, s[in_], 0, 0, 0);
      }
    }

    // causal mask + scale + online softmax
#pragma unroll
    for (int r = 0; r < 4; ++r) {
      int q_abs = q0 + w * 16 + quad * 4 + r;
      float rm = -1e30f;
#pragma unroll
      for (int in_ = 0; in_ < 4; ++in_) {
        int t_abs = j * 64 + in_ * 16 + lane16;
        float v = s[in_][r] * scale;
        v = (t_abs <= q_abs) ? v : -1e30f;
        s[in_][r] = v;
        rm = fmaxf(rm, v);
      }
#pragma unroll
      for (int m = 1; m < 16; m <<= 1) rm = fmaxf(rm, __shfl_xor(rm, m, 64));
      float mn = fmaxf(m_run[r], rm);
      float alpha = __expf(m_run[r] - mn);
      m_run[r] = mn;
      float rs = 0.f;
#pragma unroll
      for (int in_ = 0; in_ < 4; ++in_) {
        float pv = __expf(s[in_][r] - mn);
        s[in_][r] = pv;
        rs += pv;
      }
#pragma unroll
      for (int m = 1; m < 16; m <<= 1) rs += __shfl_xor(rs, m, 64);
      l_run[r] = l_run[r] * alpha + rs;
#pragma unroll
      for (int id = 0; id < 8; ++id) O[id][r] *= alpha;
#pragma unroll
      for (int in_ = 0; in_ < 4; ++in_)
        Ps[w][(quad * 4 + r) * 72 + in_ * 16 + lane16] = (bf16)s[in_][r];
    }

    // O += P @ V
#pragma unroll
    for (int kt = 0; kt < 2; ++kt) {
      bf16x8 a = *(const bf16x8*)&Ps[w][lane16 * 72 + kt * 32 + quad * 8];
#pragma unroll
      for (int id = 0; id < 8; ++id) {
        bf16x8 b = *(const bf16x8*)&Vt[(id * 16 + lane16) * 72 + kt * 32 + quad * 8];
        O[id] = __builtin_amdgcn_mfma_f32_16x16x32_bf16(a, b, O[id], 0, 0, 0);
      }
    }
    __syncthreads();
  }

  // epilogue: O /= l, write bf16
#pragma unroll
  for (int r = 0; r < 4; ++r) {
    float inv = 1.0f / l_run[r];
    int row = q0 + w * 16 + quad * 4 + r;
    bf16* orow = attn + (tok0 + row) * (size_t)HID + qh * 128;
#pragma unroll
    for (int id = 0; id < 8; ++id) orow[id * 16 + lane16] = (bf16)(O[id][r] * inv);
  }
}

// ---------------- launch ----------------
extern "C" void kernel_launch(void* const* d_in, const int* in_sizes, int n_in,
                              void* d_out, int out_size, void* d_ws, size_t ws_size,
                              hipStream_t stream) {
  const float* h    = (const float*)d_in[0];
  const int*   pos  = (const int*)d_in[1];
  const float* wqkv = (const float*)d_in[2];
  const float* wo   = (const float*)d_in[3];
  const float* qw   = (const float*)d_in[4];
  const float* kw   = (const float*)d_in[5];
  float* out = (float*)d_out;

  bf16* hb    = (bf16*)d_ws;            // 16,777,216 elems
  bf16* wqkvb = hb + 16777216;          // 25,165,824
  bf16* wob   = wqkvb + 25165824;       // 16,777,216
  bf16* qkvb  = wob + 16777216;         // 25,165,824
  bf16* attnb = qkvb + 25165824;        // 16,777,216

  cvt_kernel<<<16384, 256, 0, stream>>>((const float4*)h, (bf16x4*)hb);
  cvt_kernel<<<24576, 256, 0, stream>>>((const float4*)wqkv, (bf16x4*)wqkvb);
  cvt_kernel<<<16384, 256, 0, stream>>>((const float4*)wo, (bf16x4*)wob);

  gemm_bt<bf16><<<dim3(48, 32), 256, 0, stream>>>(hb, wqkvb, qkvb, NTOK, QKV_N, HID);

  norm_rope_kernel<<<NTOK * 40 / 4, 256, 0, stream>>>(qkvb, pos, qw, kw);

  flash_kernel<<<dim3(16, 128), 256, 0, stream>>>(qkvb, attnb);

  gemm_bt<float><<<dim3(32, 32), 256, 0, stream>>>(attnb, wob, out, NTOK, HID, HID);
}

// Round 3
// 808.361 us; speedup vs baseline: 1.3839x; 1.0824x over previous
//
#include <hip/hip_runtime.h>

typedef __bf16 bf16;
typedef __bf16 bf16x4 __attribute__((ext_vector_type(4)));
typedef __bf16 bf16x8 __attribute__((ext_vector_type(8)));
typedef float f32x4 __attribute__((ext_vector_type(4)));

#define HID 4096
#define QKV_N 6144
#define NTOK 4096   // b*s = 4*1024

// async global->LDS, 16B per lane. LDS side is wave-uniform base + lane*16.
__device__ __forceinline__ void gload_lds16(const bf16* g, bf16* l) {
  __builtin_amdgcn_global_load_lds(
      (__attribute__((address_space(1))) void*)(g),
      (__attribute__((address_space(3))) void*)(l), 16, 0, 0);
}

// ---------------- fp32 -> bf16 convert ----------------
__global__ void cvt_kernel(const float4* __restrict__ s, bf16x4* __restrict__ d) {
  int i = blockIdx.x * blockDim.x + threadIdx.x;
  float4 v = s[i];
  bf16x4 o;
  o[0] = (bf16)v.x; o[1] = (bf16)v.y; o[2] = (bf16)v.z; o[3] = (bf16)v.w;
  d[i] = o;
}

// ---------------- GEMM: C = A @ B^T (A: MxK, B: NxK, both bf16 K-major) ----------------
// 128x128 tile, BK=64, 4 waves each 64x64 (4x4 of 16x16x32 MFMA).
// LDS XOR-swizzled (R1: conflicts 7.6e7 -> 0, 610 -> 845 TF).
template <typename OutT>
__global__ __launch_bounds__(256) void gemm_bt(
    const bf16* __restrict__ A, const bf16* __restrict__ Bm,
    OutT* __restrict__ C, int M, int N, int K)
{
  __shared__ bf16 As[128 * 64];
  __shared__ bf16 Bs[128 * 64];
  const int tid = threadIdx.x;
  const int w = tid >> 6, l = tid & 63;
  const int quad = l >> 4, lane16 = l & 15;
  const int row0 = blockIdx.y * 128, col0 = blockIdx.x * 128;
  const int wm = (w & 1) * 64, wn = (w >> 1) * 64;
  const int lrow = l >> 3;                       // row within 8-row chunk
  const int lkswz = ((l & 7) ^ lrow) * 8;        // swizzled k-octet offset
  const int sw = lane16 & 7;                     // read-side swizzle key

  f32x4 acc[4][4];
#pragma unroll
  for (int a = 0; a < 4; ++a)
#pragma unroll
    for (int b = 0; b < 4; ++b) acc[a][b] = (f32x4){0.f, 0.f, 0.f, 0.f};

  for (int k0 = 0; k0 < K; k0 += 64) {
#pragma unroll
    for (int r = 0; r < 4; ++r) {
      int i = r * 4 + w;
      gload_lds16(A + (size_t)(row0 + i * 8 + lrow) * K + k0 + lkswz, &As[i * 512 + l * 8]);
      gload_lds16(Bm + (size_t)(col0 + i * 8 + lrow) * K + k0 + lkswz, &Bs[i * 512 + l * 8]);
    }
    __syncthreads();
#pragma unroll
    for (int kk = 0; kk < 2; ++kk) {
      bf16x8 af[4], bfr[4];
#pragma unroll
      for (int im = 0; im < 4; ++im)
        af[im] = *(const bf16x8*)&As[(wm + im * 16 + lane16) * 64 + (((kk * 4 + quad) ^ sw) * 8)];
#pragma unroll
      for (int in_ = 0; in_ < 4; ++in_)
        bfr[in_] = *(const bf16x8*)&Bs[(wn + in_ * 16 + lane16) * 64 + (((kk * 4 + quad) ^ sw) * 8)];
#pragma unroll
      for (int im = 0; im < 4; ++im)
#pragma unroll
        for (int in_ = 0; in_ < 4; ++in_)
          acc[im][in_] = __builtin_amdgcn_mfma_f32_16x16x32_bf16(af[im], bfr[in_], acc[im][in_], 0, 0, 0);
    }
    __syncthreads();
  }
#pragma unroll
  for (int im = 0; im < 4; ++im) {
#pragma unroll
    for (int r = 0; r < 4; ++r) {
      int row = row0 + wm + im * 16 + quad * 4 + r;
      OutT* cp = C + (size_t)row * N + col0 + wn;
#pragma unroll
      for (int in_ = 0; in_ < 4; ++in_)
        cp[in_ * 16 + lane16] = (OutT)acc[im][in_][r];
    }
  }
}

// ---------------- per-head RMSNorm + RoPE, in-place on qkv (bf16) ----------------
__global__ __launch_bounds__(256) void norm_rope_kernel(
    bf16* __restrict__ qkv, const int* __restrict__ pos,
    const float* __restrict__ qw, const float* __restrict__ kw)
{
  int g = blockIdx.x * 4 + (threadIdx.x >> 6);
  int tok = g / 40;
  int slot = g % 40;
  int d = threadIdx.x & 63;  // pair index
  bf16* base;
  const float* w;
  if (slot < 32) { base = qkv + (size_t)tok * QKV_N + slot * 128; w = qw; }
  else           { base = qkv + (size_t)tok * QKV_N + HID + (slot - 32) * 128; w = kw; }
  float x1 = (float)base[d], x2 = (float)base[d + 64];
  float ss = x1 * x1 + x2 * x2;
#pragma unroll
  for (int m = 1; m < 64; m <<= 1) ss += __shfl_xor(ss, m, 64);
  float rn = rsqrtf(ss * (1.0f / 128.0f) + 1e-6f);
  x1 = x1 * rn * w[d];
  x2 = x2 * rn * w[d + 64];
  int p = pos[tok & 1023];
  float invf = exp2f(-0.20762050593045952f * (float)d);
  float ang = (float)p * invf;
  float sn, c;
  sincosf(ang, &sn, &c);
  base[d]      = (bf16)(x1 * c - x2 * sn);
  base[d + 64] = (bf16)(x2 * c + x1 * sn);
}

// ---------------- flash attention (causal, GQA) ----------------
// grid: (16, 128). qt swizzled so co-resident blocks (ids +256k) pair qt with
// 15-qt -> constant causal work per CU. Q in registers; K/V double-buffered
// with ONE __syncthreads per iter; K prefetched a full iteration ahead via
// global_load_lds; V prefetched to regs at iter top, LDS-written after QK^T.
__global__ __launch_bounds__(256) void flash_kernel(
    const bf16* __restrict__ qkv, bf16* __restrict__ attn)
{
  __shared__ bf16 Ks[2][64 * 128];  // XOR-swizzled rows
  __shared__ bf16 Vt[2][128 * 64];  // [d][t], XOR-swizzled octets
  __shared__ bf16 Ps[4][16 * 72];   // per-wave P (C-layout -> A-layout)

  const int bh = blockIdx.y;        // 0..127
  const int qt = ((bh >> 4) & 1) ? (15 - blockIdx.x) : blockIdx.x;
  const int batch = bh >> 5;
  const int qh = bh & 31;
  const int kvh = qh >> 2;
  const int tid = threadIdx.x;
  const int w = tid >> 6, l = tid & 63;
  const int quad = l >> 4, lane16 = l & 15;
  const int sw = lane16 & 7;
  const size_t tok0 = (size_t)batch * 1024;
  const int q0 = qt * 64;

  // Q fragments from global: A[m=lane16][k=quad*8+j], rows q0 + w*16 + lane16
  bf16x8 qf[4];
  {
    const bf16* qrow = qkv + (tok0 + q0 + w * 16 + lane16) * QKV_N + qh * 128 + quad * 8;
#pragma unroll
    for (int kk = 0; kk < 4; ++kk) qf[kk] = *(const bf16x8*)(qrow + kk * 32);
  }

  f32x4 O[8];
#pragma unroll
  for (int id = 0; id < 8; ++id) O[id] = (f32x4){0.f, 0.f, 0.f, 0.f};
  float m_run[4], l_run[4];
#pragma unroll
  for (int r = 0; r < 4; ++r) { m_run[r] = -1e30f; l_run[r] = 0.f; }

  const float scale = 0.08838834764831845f;  // 1/sqrt(128)
  bf16x8 vreg[4];

  // ---- staging helpers ----
  auto stage_K = [&](int j, int buf) {
#pragma unroll
    for (int r = 0; r < 4; ++r) {
      int i = r * 4 + w;
      int rloc = i * 4 + (l >> 4);
      int o = (l & 15) ^ (rloc & 7);
      const bf16* g = qkv + (tok0 + j * 64 + rloc) * QKV_N + HID + kvh * 128 + o * 8;
      gload_lds16(g, &Ks[buf][i * 512 + l * 8]);
    }
  };
  auto load_V = [&](int j) {
#pragma unroll
    for (int c = 0; c < 4; ++c) {
      int d0 = (c * 4 + w) * 8;
      vreg[c] = *(const bf16x8*)(qkv + (tok0 + j * 64 + l) * QKV_N + HID + 1024 + kvh * 128 + d0);
    }
  };
  auto write_V = [&](int buf) {
#pragma unroll
    for (int c = 0; c < 4; ++c) {
      int d0 = (c * 4 + w) * 8;
#pragma unroll
      for (int e = 0; e < 8; ++e) {
        int d = d0 + e;
        Vt[buf][d * 64 + (((l >> 3) ^ (d & 7)) * 8) + (l & 7)] = vreg[c][e];
      }
    }
  };

  // prologue: stage j=0 into buf 0
  stage_K(0, 0);
  load_V(0);
  write_V(0);
  __syncthreads();

  for (int j = 0; j <= qt; ++j) {
    const int p = j & 1;
    // prefetch next tile (K direct to LDS, V to regs)
    if (j < qt) { stage_K(j + 1, p ^ 1); load_V(j + 1); }

    // S = Q K^T
    f32x4 s[4];
#pragma unroll
    for (int in_ = 0; in_ < 4; ++in_) s[in_] = (f32x4){0.f, 0.f, 0.f, 0.f};
#pragma unroll
    for (int kk = 0; kk < 4; ++kk) {
#pragma unroll
      for (int in_ = 0; in_ < 4; ++in_) {
        bf16x8 b = *(const bf16x8*)&Ks[p][(in_ * 16 + lane16) * 128 + (((kk * 4 + quad) ^ sw) * 8)];
        s[in_] = __builtin_amdgcn_mfma_f32_16x16x32_bf16(qf[kk], b, s[in_], 0, 0, 0);
      }
    }

    // V(j+1) regs -> LDS (overlaps with the vm latency already mostly hidden by QK)
    if (j < qt) write_V(p ^ 1);

    // softmax (mask only on diagonal tile)
    const bool edge = (j == qt);
#pragma unroll
    for (int r = 0; r < 4; ++r) {
      float rm = -1e30f;
#pragma unroll
      for (int in_ = 0; in_ < 4; ++in_) {
        float v = s[in_][r] * scale;
        if (edge) {
          int t_abs = j * 64 + in_ * 16 + lane16;
          int q_abs = q0 + w * 16 + quad * 4 + r;
          v = (t_abs <= q_abs) ? v : -1e30f;
        }
        s[in_][r] = v;
        rm = fmaxf(rm, v);
      }
#pragma unroll
      for (int m = 1; m < 16; m <<= 1) rm = fmaxf(rm, __shfl_xor(rm, m, 64));
      float mn = fmaxf(m_run[r], rm);
      float alpha = __expf(m_run[r] - mn);
      m_run[r] = mn;
      float rs = 0.f;
#pragma unroll
      for (int in_ = 0; in_ < 4; ++in_) {
        float pv = __expf(s[in_][r] - mn);
        s[in_][r] = pv;
        rs += pv;
      }
#pragma unroll
      for (int m = 1; m < 16; m <<= 1) rs += __shfl_xor(rs, m, 64);
      l_run[r] = l_run[r] * alpha + rs;
#pragma unroll
      for (int id = 0; id < 8; ++id) O[id][r] *= alpha;
#pragma unroll
      for (int in_ = 0; in_ < 4; ++in_)
        Ps[w][(quad * 4 + r) * 72 + in_ * 16 + lane16] = (bf16)s[in_][r];
    }

    // O += P @ V  (Ps is per-wave: no barrier needed, lgkmcnt dependency only)
#pragma unroll
    for (int kt = 0; kt < 2; ++kt) {
      bf16x8 a = *(const bf16x8*)&Ps[w][lane16 * 72 + kt * 32 + quad * 8];
#pragma unroll
      for (int id = 0; id < 8; ++id) {
        bf16x8 b = *(const bf16x8*)&Vt[p][(id * 16 + lane16) * 64 + (((kt * 4 + quad) ^ sw) * 8)];
        O[id] = __builtin_amdgcn_mfma_f32_16x16x32_bf16(a, b, O[id], 0, 0, 0);
      }
    }
    __syncthreads();  // buf p free for overwrite; prefetched vmcnt drained
  }

  // epilogue
#pragma unroll
  for (int r = 0; r < 4; ++r) {
    float inv = 1.0f / l_run[r];
    int row = q0 + w * 16 + quad * 4 + r;
    bf16* orow = attn + (tok0 + row) * (size_t)HID + qh * 128;
#pragma unroll
    for (int id = 0; id < 8; ++id) orow[id * 16 + lane16] = (bf16)(O[id][r] * inv);
  }
}

// ---------------- launch ----------------
extern "C" void kernel_launch(void* const* d_in, const int* in_sizes, int n_in,
                              void* d_out, int out_size, void* d_ws, size_t ws_size,
                              hipStream_t stream) {
  const float* h    = (const float*)d_in[0];
  const int*   pos  = (const int*)d_in[1];
  const float* wqkv = (const float*)d_in[2];
  const float* wo   = (const float*)d_in[3];
  const float* qw   = (const float*)d_in[4];
  const float* kw   = (const float*)d_in[5];
  float* out = (float*)d_out;

  bf16* hb    = (bf16*)d_ws;
  bf16* wqkvb = hb + 16777216;
  bf16* wob   = wqkvb + 25165824;
  bf16* qkvb  = wob + 16777216;
  bf16* attnb = qkvb + 25165824;

  cvt_kernel<<<16384, 256, 0, stream>>>((const float4*)h, (bf16x4*)hb);
  cvt_kernel<<<24576, 256, 0, stream>>>((const float4*)wqkv, (bf16x4*)wqkvb);
  cvt_kernel<<<16384, 256, 0, stream>>>((const float4*)wo, (bf16x4*)wob);

  gemm_bt<bf16><<<dim3(48, 32), 256, 0, stream>>>(hb, wqkvb, qkvb, NTOK, QKV_N, HID);

  norm_rope_kernel<<<NTOK * 40 / 4, 256, 0, stream>>>(qkvb, pos, qw, kw);

  flash_kernel<<<dim3(16, 128), 256, 0, stream>>>(qkvb, attnb);

  gemm_bt<float><<<dim3(32, 32), 256, 0, stream>>>(attnb, wob, out, NTOK, HID, HID);
}